// Round 6
// baseline (479.723 us; speedup 1.0000x reference)
//
#include <hip/hip_runtime.h>

// GraphNN R6: CSR gathers + all-MFMA GEMMs. Edge h-chain now single-compute:
//  h0 pass stores bf16 h0 in A-frag order (Plan B, ws>=160MB, runtime-checked);
//  h1 pass streams h0 -> MFMA -> h1 stats + bf16 h1 in C-frag order;
//  vals pass is a light reader. Fallback Plan C = recompute (R5) w/ 2x grid.

#define N_NODES 50000
#define N_EDGES 400000
#define N_PAIRS 200000
#define N_G     100
#define EPG     4000
#define PPG     2000
#define NCHUNK  3125   // 50000/16
#define H0SPLIT 4000   // h0f chunk boundary (tiles)

typedef float  f4   __attribute__((ext_vector_type(4)));
typedef short  bf8  __attribute__((ext_vector_type(8)));
typedef unsigned u32x4 __attribute__((ext_vector_type(4)));
typedef unsigned short ushort_t;

__device__ __forceinline__ float tanh_fast(float x) {
    float cx = fminf(15.f, fmaxf(-15.f, x));
    float e = __expf(2.f * cx);
    return (e - 1.f) * __builtin_amdgcn_rcpf(e + 1.f);
}
__device__ __forceinline__ unsigned f2bf(float f) {   // RNE fp32->bf16
    unsigned u = __float_as_uint(f);
    return (u + 0x7FFFu + ((u >> 16) & 1u)) >> 16;
}
__device__ __forceinline__ float bf2f(unsigned h) { return __uint_as_float(h << 16); }

// ---------------- CSR build ---------------------------------------------------
__global__ void k_csr_count(const int* __restrict__ edges, int* __restrict__ cnt) {
    int p = blockIdx.x * 256 + threadIdx.x;
    if (p >= N_PAIRS) return;
    atomicAdd(&cnt[edges[N_EDGES + 2 * p]], 1);
}
__global__ __launch_bounds__(512) void k_csr_scan(const int* __restrict__ cnt,
                                                  int* __restrict__ offs) {
    __shared__ int s[512];
    int g = blockIdx.x, t = threadIdx.x;
    int v = (t < 500) ? cnt[g * 500 + t] : 0;
    s[t] = v; __syncthreads();
    for (int off = 1; off < 512; off <<= 1) {
        int a = (t >= off) ? s[t - off] : 0;
        __syncthreads();
        s[t] += a; __syncthreads();
    }
    if (t < 500) offs[g * 500 + t] = g * PPG + s[t] - v;
}
__global__ void k_csr_fill(const int* __restrict__ edges, const float* __restrict__ ea,
                           const int* __restrict__ offs, int* __restrict__ fillc,
                           int* __restrict__ esrc, float* __restrict__ ew) {
    int p = blockIdx.x * 256 + threadIdx.x;
    if (p >= N_PAIRS) return;
    int d = edges[N_EDGES + 2 * p];
    int pos = offs[d] + atomicAdd(&fillc[d], 1);
    esrc[pos] = edges[2 * p];
    ew[pos] = ea[4 * p] + ea[4 * p + 2];
}

// ---------------- gathers -----------------------------------------------------
__global__ __launch_bounds__(256) void k_gath5(
    const int* __restrict__ cnt, const int* __restrict__ offs,
    const int* __restrict__ esrc, const float* __restrict__ ew,
    const float* __restrict__ x, float* __restrict__ agg) {
    int t = blockIdx.x * 256 + threadIdx.x;
    int n = t >> 3, k = t & 7;
    if (n >= N_NODES || k >= 5) return;
    int o0 = offs[n], c = cnt[n];
    float acc = 0.f;
    for (int i = o0; i < o0 + c; ++i) acc += x[esrc[i] * 5 + k] * ew[i];
    agg[n * 5 + k] = acc;
}
__global__ __launch_bounds__(256) void k_gath32(
    const int* __restrict__ cnt, const int* __restrict__ offs,
    const int* __restrict__ esrc, const float* __restrict__ ew,
    const float* __restrict__ x1, ushort_t* __restrict__ c2h, ushort_t* __restrict__ c2l) {
    int n = blockIdx.x * 8 + (threadIdx.x >> 5), k = threadIdx.x & 31;
    if (n >= N_NODES) return;
    int o0 = offs[n], c = cnt[n];
    float acc = 0.f;
    for (int i = o0; i < o0 + c; ++i) acc += x1[esrc[i] * 32 + k] * ew[i];
    unsigned hi = f2bf(acc);
    size_t o = (size_t)n * 64 + k;
    c2h[o] = (ushort_t)hi;
    c2l[o] = (ushort_t)f2bf(acc - bf2f(hi));
}
__global__ __launch_bounds__(256) void k_gath64(
    const int* __restrict__ cnt, const int* __restrict__ offs,
    const int* __restrict__ esrc, const float* __restrict__ ew,
    const float* __restrict__ x2, ushort_t* __restrict__ ch, ushort_t* __restrict__ cl) {
    int n = blockIdx.x * 4 + (threadIdx.x >> 6), k = threadIdx.x & 63;
    if (n >= N_NODES) return;
    int o0 = offs[n], c = cnt[n];
    float acc = 0.f;
    for (int i = o0; i < o0 + c; ++i) acc += x2[esrc[i] * 64 + k] * ew[i];
    unsigned hi = f2bf(acc);
    size_t o = (size_t)n * 128 + k;
    ch[o] = (ushort_t)hi;
    cl[o] = (ushort_t)f2bf(acc - bf2f(hi));
}

// ---------------- layer1 dense 5->32 ------------------------------------------
__global__ __launch_bounds__(256) void k_dense1(
    const float* __restrict__ x, const float* __restrict__ agg,
    const float* __restrict__ Wrel, const float* __restrict__ brel,
    const float* __restrict__ Wroot, float* __restrict__ x1,
    ushort_t* __restrict__ c2h, ushort_t* __restrict__ c2l) {
    __shared__ float wr[160], wt[160], bb[32];
    __shared__ float sa[8][5], sx[8][5];
    for (int i = threadIdx.x; i < 160; i += 256) { wr[i] = Wrel[i]; wt[i] = Wroot[i]; }
    if (threadIdx.x < 32) bb[threadIdx.x] = brel[threadIdx.x];
    int j = threadIdx.x & 31, nl = threadIdx.x >> 5;
    int nb = blockIdx.x * 8;
    __syncthreads();
    for (int i = threadIdx.x; i < 40; i += 256) {
        int nn = nb + i / 5, kk = i % 5;
        float av = 0.f, xv = 0.f;
        if (nn < N_NODES) { av = agg[nn * 5 + kk]; xv = x[nn * 5 + kk]; }
        sa[i / 5][kk] = av; sx[i / 5][kk] = xv;
    }
    __syncthreads();
    int n = nb + nl;
    if (n < N_NODES) {
        float acc = bb[j];
        #pragma unroll
        for (int k = 0; k < 5; ++k)
            acc += sa[nl][k] * wr[k * 32 + j] + sx[nl][k] * wt[k * 32 + j];
        float v = tanhf(acc);
        x1[n * 32 + j] = v;
        unsigned hi = f2bf(v);
        size_t o = (size_t)n * 64 + 32 + j;
        c2h[o] = (ushort_t)hi;
        c2l[o] = (ushort_t)f2bf(v - bf2f(hi));
    }
}

// ---------------- weight frag packers -----------------------------------------
__global__ void k_packWc(const float* __restrict__ Wrel2, const float* __restrict__ Wroot2,
                         unsigned* __restrict__ dst) {
    int i = blockIdx.x * 256 + threadIdx.x;   // 8192
    int t = i & 3, l = (i >> 2) & 63, kk = (i >> 8) & 3, n = i >> 10;
    int k = kk * 32 + ((l >> 4) << 3) + 2 * t;
    int j = 16 * n + (l & 15);
    float v0 = (k < 64) ? Wrel2[k * 128 + j] : Wroot2[(k - 64) * 128 + j];
    float v1 = (k + 1 < 64) ? Wrel2[(k + 1) * 128 + j] : Wroot2[(k + 1 - 64) * 128 + j];
    dst[i] = f2bf(v0) | (f2bf(v1) << 16);
}
__global__ void k_packWpq(const float* __restrict__ Wd0, unsigned* __restrict__ dst) {
    int i = blockIdx.x * 256 + threadIdx.x;   // 16384
    int t = i & 3, l = (i >> 2) & 63, kk = (i >> 8) & 3, n = i >> 10;
    int k = kk * 32 + ((l >> 4) << 3) + 2 * t;
    int j = 16 * n + (l & 15);
    float v0 = (j < 128) ? Wd0[k * 128 + j] : Wd0[(129 + k) * 128 + (j - 128)];
    float v1 = (j < 128) ? Wd0[(k + 1) * 128 + j] : Wd0[(129 + k + 1) * 128 + (j - 128)];
    dst[i] = f2bf(v0) | (f2bf(v1) << 16);
}
__global__ void k_packW2(const float* __restrict__ Wrel1, const float* __restrict__ Wroot1,
                         unsigned* __restrict__ dst) {
    int i = blockIdx.x * 256 + threadIdx.x;   // 2048
    int t = i & 3, l = (i >> 2) & 63, kk = (i >> 8) & 1, n = i >> 9;
    int k = kk * 32 + ((l >> 4) << 3) + 2 * t;
    int j = 16 * n + (l & 15);
    float v0 = (k < 32) ? Wrel1[k * 64 + j] : Wroot1[(k - 32) * 64 + j];
    float v1 = (k + 1 < 32) ? Wrel1[(k + 1) * 64 + j] : Wroot1[(k + 1 - 32) * 64 + j];
    dst[i] = f2bf(v0) | (f2bf(v1) << 16);
}

// ---------------- G1b: x2 = tanh(cat2 @ W2 + brel1) ---------------------------
__global__ __launch_bounds__(256) void k_g1b(
    const ushort_t* __restrict__ Ah, const ushort_t* __restrict__ Al,
    const unsigned* __restrict__ Wb_, const float* __restrict__ bias,
    float* __restrict__ x2, ushort_t* __restrict__ ch, ushort_t* __restrict__ cl) {
    int wave = threadIdx.x >> 6, lane = threadIdx.x & 63;
    int rl = lane & 15, gp = lane >> 4;
    int cid = blockIdx.x * 4 + wave;
    if (cid >= NCHUNK) return;
    u32x4 B[4][2];
    const u32x4* Wb = (const u32x4*)Wb_;
    #pragma unroll
    for (int n = 0; n < 4; ++n)
        #pragma unroll
        for (int kk = 0; kk < 2; ++kk)
            B[n][kk] = Wb[(n * 2 + kk) * 64 + lane];
    float bs[4];
    #pragma unroll
    for (int n = 0; n < 4; ++n) bs[n] = bias[n * 16 + rl];
    const u32x4* ph = (const u32x4*)(Ah + (size_t)(cid * 16 + rl) * 64 + gp * 8);
    const u32x4* pl = (const u32x4*)(Al + (size_t)(cid * 16 + rl) * 64 + gp * 8);
    bf8 ah[2], al4[2];
    #pragma unroll
    for (int kk = 0; kk < 2; ++kk) {
        ah[kk]  = __builtin_bit_cast(bf8, ph[kk * 4]);
        al4[kk] = __builtin_bit_cast(bf8, pl[kk * 4]);
    }
    f4 acc[4];
    #pragma unroll
    for (int n = 0; n < 4; ++n) acc[n] = (f4)0.f;
    #pragma unroll
    for (int kk = 0; kk < 2; ++kk) {
        #pragma unroll
        for (int n = 0; n < 4; ++n)
            acc[n] = __builtin_amdgcn_mfma_f32_16x16x32_bf16(
                ah[kk], __builtin_bit_cast(bf8, B[n][kk]), acc[n], 0, 0, 0);
        #pragma unroll
        for (int n = 0; n < 4; ++n)
            acc[n] = __builtin_amdgcn_mfma_f32_16x16x32_bf16(
                al4[kk], __builtin_bit_cast(bf8, B[n][kk]), acc[n], 0, 0, 0);
    }
    #pragma unroll
    for (int n = 0; n < 4; ++n)
        #pragma unroll
        for (int t = 0; t < 4; ++t) {
            float v = tanh_fast(acc[n][t] + bs[n]);
            int node = cid * 16 + gp * 4 + t;
            int col = n * 16 + rl;
            x2[(size_t)node * 64 + col] = v;
            unsigned hi = f2bf(v);
            size_t o = (size_t)node * 128 + 64 + col;
            ch[o] = (ushort_t)hi;
            cl[o] = (ushort_t)f2bf(v - bf2f(hi));
        }
}

// ---------------- G1: x3 = tanh(cat @ Wc + brel2) -----------------------------
__global__ __launch_bounds__(256) void k_g1(
    const ushort_t* __restrict__ Ah, const ushort_t* __restrict__ Al,
    const unsigned* __restrict__ Wb_, const float* __restrict__ bias,
    ushort_t* __restrict__ Oh, ushort_t* __restrict__ Ol) {
    int wave = threadIdx.x >> 6, lane = threadIdx.x & 63;
    int cg = wave & 1, mg = wave >> 1;
    int rl = lane & 15, gp = lane >> 4;
    u32x4 B[4][4];
    const u32x4* Wb = (const u32x4*)Wb_;
    #pragma unroll
    for (int n = 0; n < 4; ++n)
        #pragma unroll
        for (int kk = 0; kk < 4; ++kk)
            B[n][kk] = Wb[((cg * 4 + n) * 4 + kk) * 64 + lane];
    float bs[4];
    #pragma unroll
    for (int n = 0; n < 4; ++n) bs[n] = bias[cg * 64 + n * 16 + rl];
    for (int it = 0; it < 2; ++it) {
        int cid = (blockIdx.x * 2 + it) * 2 + mg;
        if (cid >= NCHUNK) continue;
        const u32x4* ph = (const u32x4*)(Ah + (size_t)(cid * 16 + rl) * 128 + gp * 8);
        const u32x4* pl = (const u32x4*)(Al + (size_t)(cid * 16 + rl) * 128 + gp * 8);
        bf8 ah[4], al4[4];
        #pragma unroll
        for (int kk = 0; kk < 4; ++kk) {
            ah[kk]  = __builtin_bit_cast(bf8, ph[kk * 4]);
            al4[kk] = __builtin_bit_cast(bf8, pl[kk * 4]);
        }
        f4 acc[4];
        #pragma unroll
        for (int n = 0; n < 4; ++n) acc[n] = (f4)0.f;
        #pragma unroll
        for (int kk = 0; kk < 4; ++kk) {
            #pragma unroll
            for (int n = 0; n < 4; ++n)
                acc[n] = __builtin_amdgcn_mfma_f32_16x16x32_bf16(
                    ah[kk], __builtin_bit_cast(bf8, B[n][kk]), acc[n], 0, 0, 0);
            #pragma unroll
            for (int n = 0; n < 4; ++n)
                acc[n] = __builtin_amdgcn_mfma_f32_16x16x32_bf16(
                    al4[kk], __builtin_bit_cast(bf8, B[n][kk]), acc[n], 0, 0, 0);
        }
        #pragma unroll
        for (int n = 0; n < 4; ++n)
            #pragma unroll
            for (int t = 0; t < 4; ++t) {
                float v = tanh_fast(acc[n][t] + bs[n]);
                unsigned hi = f2bf(v);
                int node = cid * 16 + gp * 4 + t;
                int col = cg * 64 + n * 16 + rl;
                Oh[(size_t)node * 128 + col] = (ushort_t)hi;
                Ol[(size_t)node * 128 + col] = (ushort_t)f2bf(v - bf2f(hi));
            }
    }
}

// ---------------- G2: [P|Q] = x3 @ Wpq (+bd0) ---------------------------------
__global__ __launch_bounds__(256) void k_g2(
    const ushort_t* __restrict__ Ah, const ushort_t* __restrict__ Al,
    const unsigned* __restrict__ Wb_, const float* __restrict__ bd0,
    float* __restrict__ P, float* __restrict__ Qb) {
    int cg = threadIdx.x >> 6, lane = threadIdx.x & 63;
    int rl = lane & 15, gp = lane >> 4;
    u32x4 B[4][4];
    const u32x4* Wb = (const u32x4*)Wb_;
    #pragma unroll
    for (int n = 0; n < 4; ++n)
        #pragma unroll
        for (int kk = 0; kk < 4; ++kk)
            B[n][kk] = Wb[((cg * 4 + n) * 4 + kk) * 64 + lane];
    float bs[4];
    #pragma unroll
    for (int n = 0; n < 4; ++n) {
        int j = cg * 64 + n * 16 + rl;
        bs[n] = (j < 128) ? bd0[j] : 0.f;
    }
    for (int it = 0; it < 2; ++it) {
        int cid = blockIdx.x * 2 + it;
        if (cid >= NCHUNK) continue;
        const u32x4* ph = (const u32x4*)(Ah + (size_t)(cid * 16 + rl) * 128 + gp * 8);
        const u32x4* pl = (const u32x4*)(Al + (size_t)(cid * 16 + rl) * 128 + gp * 8);
        bf8 ah[4], al4[4];
        #pragma unroll
        for (int kk = 0; kk < 4; ++kk) {
            ah[kk]  = __builtin_bit_cast(bf8, ph[kk * 4]);
            al4[kk] = __builtin_bit_cast(bf8, pl[kk * 4]);
        }
        f4 acc[4];
        #pragma unroll
        for (int n = 0; n < 4; ++n) acc[n] = (f4)0.f;
        #pragma unroll
        for (int kk = 0; kk < 4; ++kk) {
            #pragma unroll
            for (int n = 0; n < 4; ++n)
                acc[n] = __builtin_amdgcn_mfma_f32_16x16x32_bf16(
                    ah[kk], __builtin_bit_cast(bf8, B[n][kk]), acc[n], 0, 0, 0);
            #pragma unroll
            for (int n = 0; n < 4; ++n)
                acc[n] = __builtin_amdgcn_mfma_f32_16x16x32_bf16(
                    al4[kk], __builtin_bit_cast(bf8, B[n][kk]), acc[n], 0, 0, 0);
        }
        #pragma unroll
        for (int n = 0; n < 4; ++n) {
            int j = cg * 64 + n * 16 + rl;
            #pragma unroll
            for (int t = 0; t < 4; ++t) {
                float v = acc[n][t] + bs[n];
                int node = cid * 16 + gp * 4 + t;
                if (j < 128) P[(size_t)node * 128 + j] = v;
                else         Qb[(size_t)node * 128 + (j - 128)] = v;
            }
        }
    }
}

// ---------------- h0 pass: stats (+ optional A-frag bf16 store) ---------------
// grid N_G*16, block 4 waves; slot = tb*4+wave in [0,64); tile = slot+64j.
template<int STORE>
__global__ __launch_bounds__(256, 1) void k_h0s(
    const int* __restrict__ edges, const float* __restrict__ ea,
    const float* __restrict__ P, const float* __restrict__ Qb,
    const float* __restrict__ Wd0,
    float* __restrict__ S0, float* __restrict__ Q0s,
    u32x4* __restrict__ h0c1, u32x4* __restrict__ h0c2) {
    int g = blockIdx.x >> 4, tb = blockIdx.x & 15;
    int wave = threadIdx.x >> 6, lane = threadIdx.x & 63;
    int row = lane & 15, grp = lane >> 4;
    int slot = tb * 4 + wave;
    f4 wmr[4][2];
    #pragma unroll
    for (int kk = 0; kk < 4; ++kk) {
        const f4* wmp = (const f4*)(Wd0 + 16384 + kk * 32 + grp * 8);
        wmr[kk][0] = wmp[0]; wmr[kk][1] = wmp[1];
    }
    f4 s[4][2], q[4][2];
    #pragma unroll
    for (int kk = 0; kk < 4; ++kk)
        #pragma unroll
        for (int h = 0; h < 2; ++h) { s[kk][h] = (f4)0.f; q[kk][h] = (f4)0.f; }

    for (int j = 0; j < 2; ++j) {
        int tile = slot + 64 * j;
        if (tile >= 125) break;
        int eg0 = g * EPG + tile * 32;
        int tileG = g * 125 + tile;
        u32x4* st = 0;
        if (STORE)
            st = (tileG < H0SPLIT) ? h0c1 + (size_t)tileG * 512
                                   : h0c2 + (size_t)(tileG - H0SPLIT) * 512;
        #pragma unroll
        for (int m = 0; m < 2; ++m) {
            int e = eg0 + 16 * m + row;
            int sn = edges[e], dn = edges[N_EDGES + e];
            float w = ea[2 * e];
            const f4* Pr = (const f4*)(P + sn * 128);
            const f4* Qr = (const f4*)(Qb + dn * 128);
            #pragma unroll
            for (int kk = 0; kk < 4; ++kk) {
                int o = kk * 8 + grp * 2;
                f4 p0 = Pr[o], p1 = Pr[o + 1];
                f4 q0 = Qr[o], q1 = Qr[o + 1];
                bf8 a;
                #pragma unroll
                for (int r = 0; r < 4; ++r) {
                    float h0 = tanh_fast(p0[r] + q0[r] + w * wmr[kk][0][r]);
                    float h1 = tanh_fast(p1[r] + q1[r] + w * wmr[kk][1][r]);
                    s[kk][0][r] += h0; q[kk][0][r] += h0 * h0;
                    s[kk][1][r] += h1; q[kk][1][r] += h1 * h1;
                    if (STORE) { a[r] = (short)f2bf(h0); a[4 + r] = (short)f2bf(h1); }
                }
                if (STORE) st[(m * 4 + kk) * 64 + lane] = __builtin_bit_cast(u32x4, a);
            }
        }
    }
    #pragma unroll
    for (int kk = 0; kk < 4; ++kk)
        #pragma unroll
        for (int h = 0; h < 2; ++h)
            #pragma unroll
            for (int r = 0; r < 4; ++r) {
                float sv = s[kk][h][r], qv = q[kk][h][r];
                sv += __shfl_xor(sv, 1); sv += __shfl_xor(sv, 2);
                sv += __shfl_xor(sv, 4); sv += __shfl_xor(sv, 8);
                qv += __shfl_xor(qv, 1); qv += __shfl_xor(qv, 2);
                qv += __shfl_xor(qv, 4); qv += __shfl_xor(qv, 8);
                if (row == 0) {
                    int k = kk * 32 + grp * 8 + h * 4 + r;
                    atomicAdd(&S0[g * 128 + k], sv);
                    atomicAdd(&Q0s[g * 128 + k], qv);
                }
            }
}

// ---------------- fold gnorm0 -> W1b + gam ------------------------------------
__global__ __launch_bounds__(256) void k_fin0(
    const float* __restrict__ S0, const float* __restrict__ Q0s,
    const float* __restrict__ gnw, const float* __restrict__ gnb, const float* __restrict__ gnms,
    const float* __restrict__ Wd1, const float* __restrict__ bd1,
    unsigned* __restrict__ W1b, float* __restrict__ gam) {
    int g = blockIdx.x;
    __shared__ float al[128], be[128];
    if (threadIdx.x < 128) {
        int k = threadIdx.x;
        float S = S0[g * 128 + k], Q = Q0s[g * 128 + k];
        float mean = S * (1.f / EPG);
        float t = mean * gnms[k];
        float var = (Q - 2.f * t * S) * (1.f / EPG) + t * t;
        float a = gnw[k] * rsqrtf(var + 1e-5f);
        al[k] = a;
        be[k] = gnb[k] - a * t;
    }
    __syncthreads();
    unsigned* Wb = W1b + (size_t)g * 4096;
    for (int i = threadIdx.x; i < 4096; i += 256) {
        int t = i & 3, l = (i >> 2) & 63, kk = (i >> 8) & 3, n = i >> 10;
        int k = kk * 32 + ((l >> 4) << 3) + 2 * t;
        int j = 16 * n + (l & 15);
        unsigned lo = f2bf(al[k] * Wd1[k * 64 + j]);
        unsigned hi = f2bf(al[k + 1] * Wd1[(k + 1) * 64 + j]);
        Wb[i] = lo | (hi << 16);
    }
    if (threadIdx.x < 64) {
        int j = threadIdx.x;
        float acc = bd1[j];
        #pragma unroll 8
        for (int k = 0; k < 128; ++k) acc += be[k] * Wd1[k * 64 + j];
        gam[g * 64 + j] = acc;
    }
}

// ---------------- Plan B: h1 pass — stream h0f, MFMA, stats + h1 store --------
__global__ __launch_bounds__(256, 1) void k_h1lin(
    const u32x4* __restrict__ h0c1, const u32x4* __restrict__ h0c2,
    const unsigned* __restrict__ W1b, const float* __restrict__ gam,
    float* __restrict__ S1, float* __restrict__ Q1s, unsigned* __restrict__ h1ff) {
    int g = blockIdx.x >> 4, tb = blockIdx.x & 15;
    int wave = threadIdx.x >> 6, lane = threadIdx.x & 63;
    int col = lane & 15;
    int slot = tb * 4 + wave;
    bf8 bfr[4][4];
    {
        const u32x4* Wb = (const u32x4*)(W1b + (size_t)g * 4096);
        #pragma unroll
        for (int n = 0; n < 4; ++n)
            #pragma unroll
            for (int kk = 0; kk < 4; ++kk)
                bfr[n][kk] = __builtin_bit_cast(bf8, Wb[(n * 4 + kk) * 64 + lane]);
    }
    float gamn[4];
    #pragma unroll
    for (int n = 0; n < 4; ++n) gamn[n] = gam[g * 64 + 16 * n + col];
    float sacc[4] = {0.f, 0.f, 0.f, 0.f}, qacc[4] = {0.f, 0.f, 0.f, 0.f};

    for (int j = 0; j < 2; ++j) {
        int tile = slot + 64 * j;
        if (tile >= 125) break;
        int tileG = g * 125 + tile;
        const u32x4* src = (tileG < H0SPLIT) ? h0c1 + (size_t)tileG * 512
                                             : h0c2 + (size_t)(tileG - H0SPLIT) * 512;
        bf8 af[2][4];
        #pragma unroll
        for (int m = 0; m < 2; ++m)
            #pragma unroll
            for (int kk = 0; kk < 4; ++kk)
                af[m][kk] = __builtin_bit_cast(bf8, src[(m * 4 + kk) * 64 + lane]);
        f4 acc[2][4];
        #pragma unroll
        for (int m = 0; m < 2; ++m)
            #pragma unroll
            for (int n = 0; n < 4; ++n) acc[m][n] = (f4)0.f;
        #pragma unroll
        for (int kk = 0; kk < 4; ++kk)
            #pragma unroll
            for (int m = 0; m < 2; ++m)
                #pragma unroll
                for (int n = 0; n < 4; ++n)
                    acc[m][n] = __builtin_amdgcn_mfma_f32_16x16x32_bf16(
                        af[m][kk], bfr[n][kk], acc[m][n], 0, 0, 0);
        #pragma unroll
        for (int m = 0; m < 2; ++m)
            #pragma unroll
            for (int n = 0; n < 4; ++n) {
                float h[4];
                #pragma unroll
                for (int t = 0; t < 4; ++t) {
                    h[t] = tanh_fast(acc[m][n][t] + gamn[n]);
                    sacc[n] += h[t]; qacc[n] += h[t] * h[t];
                }
                unsigned w0 = f2bf(h[0]) | (f2bf(h[1]) << 16);
                unsigned w1 = f2bf(h[2]) | (f2bf(h[3]) << 16);
                size_t base = ((size_t)(tileG * 2 + m) * 4 + n) * 2;
                h1ff[(base + 0) * 64 + lane] = w0;
                h1ff[(base + 1) * 64 + lane] = w1;
            }
    }
    #pragma unroll
    for (int n = 0; n < 4; ++n) {
        float s = sacc[n], q = qacc[n];
        s += __shfl_xor(s, 16); s += __shfl_xor(s, 32);
        q += __shfl_xor(q, 16); q += __shfl_xor(q, 32);
        if (lane < 16) {
            atomicAdd(&S1[g * 64 + 16 * n + col], s);
            atomicAdd(&Q1s[g * 64 + 16 * n + col], q);
        }
    }
}

// ---------------- Plan B: vals pass — read h1ff, dot, pair-min ----------------
__global__ __launch_bounds__(256) void k_vals(
    const int* __restrict__ edges, const unsigned* __restrict__ h1ff,
    const float* __restrict__ ug, const float* __restrict__ cg,
    float* __restrict__ vals, float* __restrict__ outp) {
    int g = blockIdx.x >> 4, tb = blockIdx.x & 15;
    int wave = threadIdx.x >> 6, lane = threadIdx.x & 63;
    int col = lane & 15, grp = lane >> 4;
    int slot = tb * 4 + wave;
    float un[4];
    #pragma unroll
    for (int n = 0; n < 4; ++n) un[n] = ug[g * 64 + 16 * n + col];
    float cgv = cg[g];
    for (int j = 0; j < 2; ++j) {
        int tile = slot + 64 * j;
        if (tile >= 125) break;
        int tileG = g * 125 + tile;
        int eg0 = g * EPG + tile * 32;
        #pragma unroll
        for (int m = 0; m < 2; ++m) {
            float v[4] = {0.f, 0.f, 0.f, 0.f};
            #pragma unroll
            for (int n = 0; n < 4; ++n) {
                size_t base = ((size_t)(tileG * 2 + m) * 4 + n) * 2;
                unsigned w0 = h1ff[(base + 0) * 64 + lane];
                unsigned w1 = h1ff[(base + 1) * 64 + lane];
                v[0] += un[n] * bf2f(w0 & 0xFFFFu);
                v[1] += un[n] * bf2f(w0 >> 16);
                v[2] += un[n] * bf2f(w1 & 0xFFFFu);
                v[3] += un[n] * bf2f(w1 >> 16);
            }
            float rp[4];
            #pragma unroll
            for (int t = 0; t < 4; ++t) {
                float vv = v[t];
                vv += __shfl_xor(vv, 1); vv += __shfl_xor(vv, 2);
                vv += __shfl_xor(vv, 4); vv += __shfl_xor(vv, 8);
                rp[t] = vv + cgv;
            }
            if (col == 0) {
                #pragma unroll
                for (int pr = 0; pr < 2; ++pr) {
                    float va = rp[2 * pr], vb = rp[2 * pr + 1];
                    int p = ((eg0 + 16 * m + grp * 4) >> 1) + pr;
                    vals[p] = fminf(va, vb);
                    outp[600000 + p] = (vb < va) ? 1.f : 0.f;
                    int e = 2 * p;
                    outp[p]          = (float)edges[e];
                    outp[200000 + p] = (float)edges[N_EDGES + e];
                }
            }
        }
    }
}

// ---------------- Plan C: h1 pass w/ gather recompute (stats or vals) ---------
template<int DO_VALS>
__global__ __launch_bounds__(256, 1) void k_h1m(
    const int* __restrict__ edges, const float* __restrict__ ea,
    const float* __restrict__ P, const float* __restrict__ Qb,
    const float* __restrict__ Wd0,
    const unsigned* __restrict__ W1b, const float* __restrict__ gam,
    const float* __restrict__ ug, const float* __restrict__ cg,
    float* __restrict__ S1, float* __restrict__ Q1s,
    float* __restrict__ vals, float* __restrict__ outp) {
    int g = blockIdx.x >> 4, tb = blockIdx.x & 15;
    int wave = threadIdx.x >> 6, lane = threadIdx.x & 63;
    int col = lane & 15, grp = lane >> 4;
    int slot = tb * 4 + wave;
    bf8 bfr[4][4];
    {
        const u32x4* Wb = (const u32x4*)(W1b + (size_t)g * 4096);
        #pragma unroll
        for (int n = 0; n < 4; ++n)
            #pragma unroll
            for (int kk = 0; kk < 4; ++kk)
                bfr[n][kk] = __builtin_bit_cast(bf8, Wb[(n * 4 + kk) * 64 + lane]);
    }
    f4 wmr[4][2];
    #pragma unroll
    for (int kk = 0; kk < 4; ++kk) {
        const f4* wmp = (const f4*)(Wd0 + 16384 + kk * 32 + grp * 8);
        wmr[kk][0] = wmp[0]; wmr[kk][1] = wmp[1];
    }
    float gamn[4], un[4] = {0.f, 0.f, 0.f, 0.f};
    #pragma unroll
    for (int n = 0; n < 4; ++n) gamn[n] = gam[g * 64 + 16 * n + col];
    float cgv = 0.f;
    if (DO_VALS) {
        #pragma unroll
        for (int n = 0; n < 4; ++n) un[n] = ug[g * 64 + 16 * n + col];
        cgv = cg[g];
    }
    float sacc[4] = {0.f, 0.f, 0.f, 0.f}, qacc[4] = {0.f, 0.f, 0.f, 0.f};
    for (int j = 0; j < 2; ++j) {
        int tile = slot + 64 * j;
        if (tile >= 125) break;
        int eg0 = g * EPG + tile * 32;
        bf8 af[2][4];
        #pragma unroll
        for (int m = 0; m < 2; ++m) {
            int e = eg0 + 16 * m + col;
            int sn = edges[e], dn = edges[N_EDGES + e];
            float w = ea[2 * e];
            const f4* Pr = (const f4*)(P + sn * 128);
            const f4* Qr = (const f4*)(Qb + dn * 128);
            #pragma unroll
            for (int kk = 0; kk < 4; ++kk) {
                int o = kk * 8 + grp * 2;
                f4 p0 = Pr[o], p1 = Pr[o + 1];
                f4 q0 = Qr[o], q1 = Qr[o + 1];
                bf8 a;
                #pragma unroll
                for (int r = 0; r < 4; ++r) {
                    float h0 = tanh_fast(p0[r] + q0[r] + w * wmr[kk][0][r]);
                    float h1 = tanh_fast(p1[r] + q1[r] + w * wmr[kk][1][r]);
                    a[r]     = (short)f2bf(h0);
                    a[4 + r] = (short)f2bf(h1);
                }
                af[m][kk] = a;
            }
        }
        f4 acc[2][4];
        #pragma unroll
        for (int m = 0; m < 2; ++m)
            #pragma unroll
            for (int n = 0; n < 4; ++n) acc[m][n] = (f4)0.f;
        #pragma unroll
        for (int kk = 0; kk < 4; ++kk)
            #pragma unroll
            for (int m = 0; m < 2; ++m)
                #pragma unroll
                for (int n = 0; n < 4; ++n)
                    acc[m][n] = __builtin_amdgcn_mfma_f32_16x16x32_bf16(
                        af[m][kk], bfr[n][kk], acc[m][n], 0, 0, 0);
        if (DO_VALS) {
            float rp[2][4];
            #pragma unroll
            for (int m = 0; m < 2; ++m)
                #pragma unroll
                for (int t = 0; t < 4; ++t) {
                    float v = 0.f;
                    #pragma unroll
                    for (int n = 0; n < 4; ++n)
                        v += un[n] * tanh_fast(acc[m][n][t] + gamn[n]);
                    v += __shfl_xor(v, 1); v += __shfl_xor(v, 2);
                    v += __shfl_xor(v, 4); v += __shfl_xor(v, 8);
                    rp[m][t] = v + cgv;
                }
            if (col == 0) {
                #pragma unroll
                for (int m = 0; m < 2; ++m)
                    #pragma unroll
                    for (int pr = 0; pr < 2; ++pr) {
                        float va = rp[m][2 * pr], vb = rp[m][2 * pr + 1];
                        int p = ((eg0 + 16 * m + grp * 4) >> 1) + pr;
                        vals[p] = fminf(va, vb);
                        outp[600000 + p] = (vb < va) ? 1.f : 0.f;
                        int e = 2 * p;
                        outp[p]          = (float)edges[e];
                        outp[200000 + p] = (float)edges[N_EDGES + e];
                    }
            }
        } else {
            #pragma unroll
            for (int m = 0; m < 2; ++m)
                #pragma unroll
                for (int n = 0; n < 4; ++n)
                    #pragma unroll
                    for (int t = 0; t < 4; ++t) {
                        float h = tanh_fast(acc[m][n][t] + gamn[n]);
                        sacc[n] += h; qacc[n] += h * h;
                    }
        }
    }
    if (!DO_VALS) {
        #pragma unroll
        for (int n = 0; n < 4; ++n) {
            float s = sacc[n], q = qacc[n];
            s += __shfl_xor(s, 16); s += __shfl_xor(s, 32);
            q += __shfl_xor(q, 16); q += __shfl_xor(q, 32);
            if (lane < 16) {
                atomicAdd(&S1[g * 64 + 16 * n + col], s);
                atomicAdd(&Q1s[g * 64 + 16 * n + col], q);
            }
        }
    }
}

// ---------------- fold gnorm1 into Wout ---------------------------------------
__global__ void k_fin1(const float* __restrict__ S1, const float* __restrict__ Q1s,
                       const float* __restrict__ gnw, const float* __restrict__ gnb,
                       const float* __restrict__ gnms,
                       const float* __restrict__ Wout, const float* __restrict__ bout,
                       float* __restrict__ ug, float* __restrict__ cg) {
    int g = blockIdx.x; int j = threadIdx.x;  // 64 threads
    float S = S1[g * 64 + j], Q = Q1s[g * 64 + j];
    float mean = S * (1.f / EPG);
    float t = mean * gnms[j];
    float var = (Q - 2.f * t * S) * (1.f / EPG) + t * t;
    float a = gnw[j] * rsqrtf(var + 1e-5f);
    float b = gnb[j] - a * t;
    ug[g * 64 + j] = a * Wout[j];
    float c = b * Wout[j];
    #pragma unroll
    for (int off = 32; off; off >>= 1) c += __shfl_xor(c, off);
    if (j == 0) cg[g] = c + bout[0];
}

// ---------------- per-graph softmax -------------------------------------------
__global__ __launch_bounds__(256) void k_softmax(const float* __restrict__ vals,
                                                 float* __restrict__ outp) {
    int g = blockIdx.x;
    __shared__ float rbuf[4], rbuf2[4];
    int t = threadIdx.x;
    const float* v = vals + g * PPG;
    float mx = -1e30f;
    for (int i = t; i < PPG; i += 256) mx = fmaxf(mx, v[i]);
    #pragma unroll
    for (int off = 32; off; off >>= 1) mx = fmaxf(mx, __shfl_xor(mx, off));
    if ((t & 63) == 0) rbuf[t >> 6] = mx;
    __syncthreads();
    mx = fmaxf(fmaxf(rbuf[0], rbuf[1]), fmaxf(rbuf[2], rbuf[3]));
    float sm = 0.f;
    for (int i = t; i < PPG; i += 256) sm += expf(v[i] - mx);
    #pragma unroll
    for (int off = 32; off; off >>= 1) sm += __shfl_xor(sm, off);
    if ((t & 63) == 0) rbuf2[t >> 6] = sm;
    __syncthreads();
    sm = rbuf2[0] + rbuf2[1] + rbuf2[2] + rbuf2[3];
    for (int i = t; i < PPG; i += 256)
        outp[400000 + g * PPG + i] = expf(v[i] - mx) / (sm + 1e-16f);
}

extern "C" void kernel_launch(void* const* d_in, const int* in_sizes, int n_in,
                              void* d_out, int out_size, void* d_ws, size_t ws_size,
                              hipStream_t stream) {
    const float* x     = (const float*)d_in[0];
    const int*   edges = (const int*)d_in[1];
    const float* ea    = (const float*)d_in[2];
    const float* Wrel0 = (const float*)d_in[6],  *brel0 = (const float*)d_in[7],  *Wroot0 = (const float*)d_in[8];
    const float* Wrel1 = (const float*)d_in[9],  *brel1 = (const float*)d_in[10], *Wroot1 = (const float*)d_in[11];
    const float* Wrel2 = (const float*)d_in[12], *brel2 = (const float*)d_in[13], *Wroot2 = (const float*)d_in[14];
    const float* Wd0 = (const float*)d_in[15],  *bd0 = (const float*)d_in[16];
    const float* gnw0 = (const float*)d_in[17], *gnb0 = (const float*)d_in[18], *gnms0 = (const float*)d_in[19];
    const float* Wd1 = (const float*)d_in[20],  *bd1 = (const float*)d_in[21];
    const float* gnw1 = (const float*)d_in[22], *gnb1 = (const float*)d_in[23], *gnms1 = (const float*)d_in[24];
    const float* Wout = (const float*)d_in[25], *bout = (const float*)d_in[26];
    float* o = (float*)d_out;
    float* w = (float*)d_ws;

    // region A [0, 8.25M): early node tensors; dead by k_h0s (Plan B: h0f chunk1)
    float* agg5 = w;
    float* x1   = w + 250000;
    float* x2   = w + 1850000;
    ushort_t* c2h = (ushort_t*)(w + 5050000);
    ushort_t* c2l = (ushort_t*)(w + 6650000);
    ushort_t* x3h = (ushort_t*)(w + 0);
    ushort_t* x3l = (ushort_t*)(w + 3200000);
    // region B [8.25M, 21.05M): cat planes -> P|Qb -> (Plan B) h1ff
    float* P    = w + 8250000;
    float* Qb   = w + 14650000;
    ushort_t* cath = (ushort_t*)(w + 8250000);
    ushort_t* catl = (ushort_t*)(w + 11450000);
    unsigned* h1ff = (unsigned*)(w + 8250000);   // 12.8M u32 (Plan B, after h0s)
    // tail [21.05M, 22.4M)
    float* tail = w + 21050000;
    unsigned* Wcb  = (unsigned*)tail;
    unsigned* Wpqb = Wcb + 8192;
    unsigned* W2b  = Wpqb + 16384;
    int* cnt   = (int*)(W2b + 2048);
    int* fillc = cnt + 50000;
    int* offs  = fillc + 50000;
    int* esrc  = offs + 50000;
    float* ew  = (float*)(esrc + 200000);
    float* S0  = ew + 200000;
    float* Q0s = S0 + 12800;
    unsigned* W1b = (unsigned*)(Q0s + 12800);
    float* gam = (float*)(W1b + 409600);
    float* S1  = gam + 6400;
    float* Q1s = S1 + 6400;
    float* ug  = Q1s + 6400;
    float* cg  = ug + 6400;
    float* vals = cg + 100;
    // Plan B h0f: chunk1 overlays region A; chunk2 beyond tail
    u32x4* h0c1 = (u32x4*)w;                       // 4000 tiles * 2048 u32
    u32x4* h0c2 = (u32x4*)(w + 22400000);          // 8500 tiles * 2048 u32
    const bool planB = ws_size >= 159232000ULL;    // 39.808M floats

    hipMemsetAsync(cnt, 0, 100000 * sizeof(int), stream);
    hipMemsetAsync(S0, 0, 25600 * sizeof(float), stream);
    hipMemsetAsync(S1, 0, 12800 * sizeof(float), stream);

    k_packWc<<<32, 256, 0, stream>>>(Wrel2, Wroot2, Wcb);
    k_packWpq<<<64, 256, 0, stream>>>(Wd0, Wpqb);
    k_packW2<<<8, 256, 0, stream>>>(Wrel1, Wroot1, W2b);

    k_csr_count<<<782, 256, 0, stream>>>(edges, cnt);
    k_csr_scan<<<N_G, 512, 0, stream>>>(cnt, offs);
    k_csr_fill<<<782, 256, 0, stream>>>(edges, ea, offs, fillc, esrc, ew);

    k_gath5<<<1563, 256, 0, stream>>>(cnt, offs, esrc, ew, x, agg5);
    k_dense1<<<6250, 256, 0, stream>>>(x, agg5, Wrel0, brel0, Wroot0, x1, c2h, c2l);
    k_gath32<<<6250, 256, 0, stream>>>(cnt, offs, esrc, ew, x1, c2h, c2l);
    k_g1b<<<782, 256, 0, stream>>>(c2h, c2l, W2b, brel1, x2, cath, catl);
    k_gath64<<<12500, 256, 0, stream>>>(cnt, offs, esrc, ew, x2, cath, catl);

    k_g1<<<(NCHUNK + 3) / 4, 256, 0, stream>>>(cath, catl, Wcb, brel2, x3h, x3l);
    k_g2<<<(NCHUNK + 1) / 2, 256, 0, stream>>>(x3h, x3l, Wpqb, bd0, P, Qb);

    if (planB) {
        k_h0s<1><<<N_G * 16, 256, 0, stream>>>(edges, ea, P, Qb, Wd0, S0, Q0s, h0c1, h0c2);
        k_fin0<<<N_G, 256, 0, stream>>>(S0, Q0s, gnw0, gnb0, gnms0, Wd1, bd1, W1b, gam);
        k_h1lin<<<N_G * 16, 256, 0, stream>>>(h0c1, h0c2, W1b, gam, S1, Q1s, h1ff);
        k_fin1<<<N_G, 64, 0, stream>>>(S1, Q1s, gnw1, gnb1, gnms1, Wout, bout, ug, cg);
        k_vals<<<N_G * 16, 256, 0, stream>>>(edges, h1ff, ug, cg, vals, o);
    } else {
        k_h0s<0><<<N_G * 16, 256, 0, stream>>>(edges, ea, P, Qb, Wd0, S0, Q0s, h0c1, h0c2);
        k_fin0<<<N_G, 256, 0, stream>>>(S0, Q0s, gnw0, gnb0, gnms0, Wd1, bd1, W1b, gam);
        k_h1m<0><<<N_G * 16, 256, 0, stream>>>(edges, ea, P, Qb, Wd0, W1b, gam,
                                               ug, cg, S1, Q1s, vals, o);
        k_fin1<<<N_G, 64, 0, stream>>>(S1, Q1s, gnw1, gnb1, gnms1, Wout, bout, ug, cg);
        k_h1m<1><<<N_G * 16, 256, 0, stream>>>(edges, ea, P, Qb, Wd0, W1b, gam,
                                               ug, cg, S1, Q1s, vals, o);
    }

    k_softmax<<<N_G, 256, 0, stream>>>(vals, o);
}